// Round 3
// baseline (382.345 us; speedup 1.0000x reference)
//
#include <hip/hip_runtime.h>

// DenseGINEConv fused kernel for MI355X (gfx950).
// B=4, N=512, F=64, H=128, fp32. Memory-bound on edge_attr (256 MiB read-once).
// Round 3: per-block rotation of the i-walk. The ea stride per i is 2^17 B;
// with all blocks walking i in lockstep the instantaneous footprint hits a
// narrow subset of HBM channel granules (4 KiB) -> channel imbalance.
// Rotating each block's i start by a block-dependent multiple of 8 spreads
// concurrent accesses over all i rows -> all channels.
// Block = (b, j0..j0+3): 512 threads = 8 ip x 4 jl x 16 f4.

namespace {

constexpr int Bc = 4;
constexpr int Nc = 512;
constexpr int Fc = 64;
constexpr int Hc = 128;
constexpr int TJ = 4;          // j-tile per block
constexpr int TH = 512;        // threads per block
constexpr float NEG = 0.01f;

__device__ __forceinline__ float lrelu(float z) {
  return z > 0.f ? z : z * NEG;
}

__global__ __launch_bounds__(TH, 4) void gine_fused(
    const float* __restrict__ x,    // (B,N,F)
    const float* __restrict__ adj,  // (B,N,N)
    const float* __restrict__ ea,   // (B,N,N,F)
    const int* __restrict__ mask,   // (B,N) int32 0/1
    const float* __restrict__ W1,   // (F,H)
    const float* __restrict__ b1,   // (H)
    const float* __restrict__ W2,   // (H,F)
    const float* __restrict__ b2,   // (F)
    float* __restrict__ out)        // (B,N,F)
{
  const int blk = blockIdx.x;            // 0 .. B*N/TJ-1 = 511
  const int b   = blk >> 7;              // blk / (N/TJ = 128)
  const int j0  = (blk & 127) * TJ;
  const int tid = threadIdx.x;
  const int f4  = tid & 15;              // float4 group over F
  const int jl  = (tid >> 4) & 3;        // which j within tile
  const int ip  = tid >> 6;              // 0..7 partial over source i

  __shared__ float4 s_adj4[Nc];          // [i] = adj[b,i,j0..j0+3]
  __shared__ float4 s_part[TH];
  __shared__ float  s_out[TJ][Fc];
  __shared__ float  s_hid[TJ][Hc];

  // ---- stage adj columns j0..j0+3 (8 KiB; 16B/lane strided, L2-shared) ----
  const float* adjb = adj + (size_t)b * Nc * Nc;
  s_adj4[tid] = *reinterpret_cast<const float4*>(adjb + (size_t)tid * Nc + j0);
  __syncthreads();

  // ---- aggregation: acc[jl][f] = sum_i lrelu(adj[b,i,j0+jl]*(x[b,i,f]+ea[b,i,j0+jl,f])) ----
  const float4* xb4 = reinterpret_cast<const float4*>(x + (size_t)b * Nc * Fc);
  const float4* eap = reinterpret_cast<const float4*>(ea)
                    + ((size_t)b * Nc * Nc + (j0 + jl)) * (Fc / 4) + f4;
  constexpr int ISTRIDE = Nc * Fc / 4;   // 8192 float4s = 128 KiB per i

  // Block-dependent rotation of the i-walk start (multiple of 8 so the
  // wrapped segment keeps the ip-partitioning clean).
  const int rot = ((blk * 5) & 63) << 3;   // in {0, 8, ..., 504}

  float4 acc = make_float4(0.f, 0.f, 0.f, 0.f);

  #pragma unroll 4
  for (int i = rot + ip; i < Nc; i += 8) {
    const float a   = reinterpret_cast<const float*>(&s_adj4[i])[jl];
    const float4 xv = xb4[i * (Fc / 4) + f4];
    const float4 ev = eap[(size_t)i * ISTRIDE];
    acc.x += lrelu(a * (xv.x + ev.x));
    acc.y += lrelu(a * (xv.y + ev.y));
    acc.z += lrelu(a * (xv.z + ev.z));
    acc.w += lrelu(a * (xv.w + ev.w));
  }
  #pragma unroll 4
  for (int i = ip; i < rot; i += 8) {
    const float a   = reinterpret_cast<const float*>(&s_adj4[i])[jl];
    const float4 xv = xb4[i * (Fc / 4) + f4];
    const float4 ev = eap[(size_t)i * ISTRIDE];
    acc.x += lrelu(a * (xv.x + ev.x));
    acc.y += lrelu(a * (xv.y + ev.y));
    acc.z += lrelu(a * (xv.z + ev.z));
    acc.w += lrelu(a * (xv.w + ev.w));
  }

  // ---- reduce 8 ip-partials; partials for (jl,f4) live at stride 64 ----
  s_part[tid] = acc;
  __syncthreads();
  #pragma unroll
  for (int s = 256; s >= 64; s >>= 1) {
    if (tid < s) {
      float4 p = s_part[tid];
      const float4 q = s_part[tid + s];
      p.x += q.x; p.y += q.y; p.z += q.z; p.w += q.w;
      s_part[tid] = p;
    }
    __syncthreads();
  }

  // ---- add self-loop x[b,j,:] (EPS=0), stash 4 rows ----
  if (tid < 64) {
    const int row = tid >> 4;            // 0..3
    const int fg  = tid & 15;
    float4 r = s_part[tid];
    const float4 xj = xb4[(j0 + row) * (Fc / 4) + fg];
    r.x += xj.x; r.y += xj.y; r.z += xj.z; r.w += xj.w;
    reinterpret_cast<float4*>(&s_out[row][0])[fg] = r;
  }
  __syncthreads();

  // ---- MLP stage 1: hid[row][h] = lrelu(row @ W1 + b1); all 512 threads ----
  {
    const int row = tid >> 7;            // 0..3
    const int h   = tid & 127;
    float hv = b1[h];
    #pragma unroll 8
    for (int f = 0; f < Fc; ++f)
      hv = fmaf(s_out[row][f], W1[f * Hc + h], hv);  // coalesced over h
    s_hid[row][h] = lrelu(hv);
  }
  __syncthreads();

  // ---- MLP stage 2: o = hid @ W2 + b2, masked write (256 threads) ----
  if (tid < TJ * Fc) {
    const int row = tid >> 6;            // 0..3
    const int f   = tid & 63;
    float o = b2[f];
    #pragma unroll 8
    for (int h = 0; h < Hc; ++h)
      o = fmaf(s_hid[row][h], W2[h * Fc + f], o);
    const int rowg = b * Nc + j0 + row;
    out[rowg * Fc + f] = (mask[rowg] != 0) ? o : 0.f;
  }
}

} // namespace

extern "C" void kernel_launch(void* const* d_in, const int* in_sizes, int n_in,
                              void* d_out, int out_size, void* d_ws, size_t ws_size,
                              hipStream_t stream) {
  const float* x    = (const float*)d_in[0];
  const float* adj  = (const float*)d_in[1];
  const float* ea   = (const float*)d_in[2];
  const int*   mask = (const int*)d_in[3];
  const float* W1   = (const float*)d_in[4];
  const float* b1   = (const float*)d_in[5];
  const float* W2   = (const float*)d_in[6];
  const float* b2   = (const float*)d_in[7];
  float* out = (float*)d_out;

  gine_fused<<<dim3(Bc * Nc / TJ), dim3(TH), 0, stream>>>(
      x, adj, ea, mask, W1, b1, W2, b2, out);
}